// Round 2
// baseline (389.449 us; speedup 1.0000x reference)
//
#include <hip/hip_runtime.h>

#define IN_DIM  16
#define HID_DIM 64
#define OUT_DIM 32

// ---------------------------------------------------------------------------
// Edge dtype: reference says int64, harness doc says int32. Detect at runtime:
// nonneg int64 < 2^31 has every odd 32-bit word == 0 (prob of false positive
// with random int32 in [0,50000): ~(1/50000)^16 ~ 0).
// ---------------------------------------------------------------------------
__device__ __forceinline__ long long edge_at(const void* edges, int is64, long long i) {
    if (is64) return ((const long long*)edges)[i];
    return (long long)((const int*)edges)[i];
}

__global__ void k_detect_dtype(const void* edges, int* flag) {
    if (threadIdx.x == 0 && blockIdx.x == 0) {
        const int* w = (const int*)edges;
        int is64 = 1;
        for (int i = 0; i < 16; ++i) {
            if (w[2 * i + 1] != 0) { is64 = 0; break; }
        }
        *flag = is64;
    }
}

// zero the degree array (ws is poisoned 0xAA)
__global__ void k_zero(int* p, int n) {
    int i = blockIdx.x * 256 + threadIdx.x;
    if (i < n) p[i] = 0;
}

// degoffs[dst[e]]++ for each real edge
__global__ void k_count(const void* edges, const int* flag, int* degoffs, long long E) {
    long long e = blockIdx.x * 256LL + threadIdx.x;
    if (e >= E) return;
    long long d = edge_at(edges, *flag, E + e);
    atomicAdd(&degoffs[d], 1);
}

// Single-block scan: degoffs (degree) -> exclusive offsets (in place, +offs[N]),
// cursor = copy of offsets, dinv = rsqrt(deg+1) (self-loop included in degree).
__global__ __launch_bounds__(1024) void k_scan(int* degoffs, int* cursor, float* dinv, int N) {
    __shared__ int part[1024];
    int t = threadIdx.x;
    int chunk = (N + 1023) >> 10;
    int lo = t * chunk;
    int hi = min(lo + chunk, N);
    int s = 0;
    for (int i = lo; i < hi; ++i) s += degoffs[i];
    part[t] = s;
    __syncthreads();
    for (int d = 1; d < 1024; d <<= 1) {
        int v = (t >= d) ? part[t - d] : 0;
        __syncthreads();
        part[t] += v;
        __syncthreads();
    }
    int run = (t == 0) ? 0 : part[t - 1];
    for (int i = lo; i < hi; ++i) {
        int dv = degoffs[i];
        degoffs[i] = run;
        cursor[i]  = run;
        dinv[i]    = rsqrtf((float)dv + 1.0f);
        run += dv;
    }
    if (t == 1023) degoffs[N] = run;
}

// CSR build: csr[pos] = src, pos = cursor[dst]++
__global__ void k_place(const void* edges, const int* flag, int* cursor, int* csr, long long E) {
    long long e = blockIdx.x * 256LL + threadIdx.x;
    if (e >= E) return;
    int is64 = *flag;
    long long s = edge_at(edges, is64, e);
    long long d = edge_at(edges, is64, E + e);
    int pos = atomicAdd(&cursor[d], 1);
    csr[pos] = (int)s;
}

// Layer-1 gather-aggregate: one wave per node, lanes = 16 ch x 4 edges.
// aggX[i][c] = dinv_i * (dinv_i * x[i][c] + sum_e dinv_s * x[s][c])
__global__ void k_agg1(const float* __restrict__ x, const float* __restrict__ dinv,
                       const int* __restrict__ offs, const int* __restrict__ csr,
                       float* __restrict__ aggX, int N) {
    int node = (blockIdx.x * 256 + threadIdx.x) >> 6;
    if (node >= N) return;
    int lane = threadIdx.x & 63;
    int c = lane & 15, j0 = lane >> 4;        // j0 in [0,4)
    float di = dinv[node];
    int start = offs[node];
    int n = offs[node + 1] - start;
    float acc = (j0 == 0) ? di * x[node * IN_DIM + c] : 0.f;
    for (int j = j0; j < n; j += 4) {
        int s = csr[start + j];
        acc += dinv[s] * x[s * IN_DIM + c];
    }
    acc += __shfl_xor(acc, 16, 64);
    acc += __shfl_xor(acc, 32, 64);
    if (lane < 16) aggX[node * IN_DIM + c] = di * acc;
}

// h1 = relu(aggX @ W1 + b1)   [N,16] @ [16,64]
__global__ void k_gemm1_relu(const float* __restrict__ aggX, const float* __restrict__ W1,
                             const float* __restrict__ b1, float* __restrict__ h1, int N) {
    __shared__ float Ws[IN_DIM * HID_DIM];   // 4 KB
    __shared__ float Xs[4][IN_DIM];
    int tid = threadIdx.x;
    for (int i = tid; i < IN_DIM * HID_DIM; i += 256) Ws[i] = W1[i];
    int node0 = blockIdx.x * 4;
    if (tid < 64) {
        int r = tid >> 4, c = tid & 15;
        int node = node0 + r;
        Xs[r][c] = (node < N) ? aggX[node * IN_DIM + c] : 0.f;
    }
    __syncthreads();
    int col = tid & 63, r = tid >> 6;
    int node = node0 + r;
    if (node < N) {
        float acc = b1[col];
        #pragma unroll
        for (int k = 0; k < IN_DIM; ++k) acc += Xs[r][k] * Ws[k * HID_DIM + col];
        h1[node * HID_DIM + col] = fmaxf(acc, 0.f);
    }
}

// h2 = h1 @ W2   [N,64] @ [64,32]
__global__ void k_gemm2(const float* __restrict__ h1, const float* __restrict__ W2,
                        float* __restrict__ h2, int N) {
    __shared__ float Ws[HID_DIM * OUT_DIM];  // 8 KB
    __shared__ float Xs[8][HID_DIM];
    int tid = threadIdx.x;
    for (int i = tid; i < HID_DIM * OUT_DIM; i += 256) Ws[i] = W2[i];
    int node0 = blockIdx.x * 8;
    for (int i = tid; i < 8 * HID_DIM; i += 256) {
        int r = i >> 6, c = i & 63;
        int node = node0 + r;
        Xs[r][c] = (node < N) ? h1[node * HID_DIM + c] : 0.f;
    }
    __syncthreads();
    int col = tid & 31, r = tid >> 5;
    int node = node0 + r;
    if (node < N) {
        float acc = 0.f;
        #pragma unroll
        for (int k = 0; k < HID_DIM; ++k) acc += Xs[r][k] * Ws[k * OUT_DIM + col];
        h2[node * OUT_DIM + col] = acc;
    }
}

// Layer-2 gather-aggregate: one wave per node, lanes = 32 ch x 2 edges.
// out[i][c] = b2[c] + dinv_i * (dinv_i * h2[i][c] + sum_e dinv_s * h2[s][c])
__global__ void k_agg2(const float* __restrict__ h2, const float* __restrict__ dinv,
                       const int* __restrict__ offs, const int* __restrict__ csr,
                       const float* __restrict__ b2, float* __restrict__ out, int N) {
    int node = (blockIdx.x * 256 + threadIdx.x) >> 6;
    if (node >= N) return;
    int lane = threadIdx.x & 63;
    int c = lane & 31, j0 = lane >> 5;        // j0 in [0,2)
    float di = dinv[node];
    int start = offs[node];
    int n = offs[node + 1] - start;
    float acc = (j0 == 0) ? di * h2[node * OUT_DIM + c] : 0.f;
    for (int j = j0; j < n; j += 2) {
        int s = csr[start + j];
        acc += dinv[s] * h2[s * OUT_DIM + c];
    }
    acc += __shfl_xor(acc, 32, 64);
    if (lane < 32) out[node * OUT_DIM + c] = di * acc + b2[c];
}

extern "C" void kernel_launch(void* const* d_in, const int* in_sizes, int n_in,
                              void* d_out, int out_size, void* d_ws, size_t ws_size,
                              hipStream_t stream) {
    const float* x     = (const float*)d_in[0];
    const void*  edges = d_in[1];
    const float* W1    = (const float*)d_in[2];
    const float* b1    = (const float*)d_in[3];
    const float* W2    = (const float*)d_in[4];
    const float* b2    = (const float*)d_in[5];
    float* out = (float*)d_out;

    const int       N = in_sizes[0] / IN_DIM;   // 50000
    const long long E = in_sizes[1] / 2;        // 800000

    // workspace layout (floats):
    //   dinv [0,N) | h2 [N, 33N)  (first 16N doubles as aggX — aggX dead
    //   before gemm2 writes h2) | h1 [33N, 97N)
    // then ints: degoffs [N+1] | cursor [N] | csr [E] | flag [1]
    float* fbase  = (float*)d_ws;
    float* dinv   = fbase;                   // N
    float* h2     = fbase + N;               // 32N
    float* aggX   = h2;                      // 16N (aliases h2 front half)
    float* h1     = fbase + (size_t)33 * N;  // 64N
    int*   ibase  = (int*)(fbase + (size_t)97 * N);
    int*   degoffs = ibase;                  // N+1
    int*   cursor  = degoffs + N + 1;        // N
    int*   csr     = cursor + N;             // E
    int*   flag    = csr + E;                // 1

    const int B = 256;
    k_detect_dtype<<<1, 1, 0, stream>>>(edges, flag);
    k_zero<<<(N + 1 + B - 1) / B, B, 0, stream>>>(degoffs, N + 1);
    k_count<<<(int)((E + B - 1) / B), B, 0, stream>>>(edges, flag, degoffs, E);
    k_scan<<<1, 1024, 0, stream>>>(degoffs, cursor, dinv, N);
    k_place<<<(int)((E + B - 1) / B), B, 0, stream>>>(edges, flag, cursor, csr, E);

    // one wave per node -> 4 nodes per 256-thread block
    k_agg1<<<(N + 3) / 4, B, 0, stream>>>(x, dinv, degoffs, csr, aggX, N);
    k_gemm1_relu<<<(N + 3) / 4, B, 0, stream>>>(aggX, W1, b1, h1, N);
    k_gemm2<<<(N + 7) / 8, B, 0, stream>>>(h1, W2, h2, N);
    k_agg2<<<(N + 3) / 4, B, 0, stream>>>(h2, dinv, degoffs, csr, b2, out, N);
}

// Round 3
// 261.917 us; speedup vs baseline: 1.4869x; 1.4869x over previous
//
#include <hip/hip_runtime.h>

#define IN_DIM  16
#define HID_DIM 64
#define OUT_DIM 32

// ---------------------------------------------------------------------------
// Edge dtype: reference says int64, harness doc says int32. Detect at runtime:
// nonneg int64 < 2^31 has every odd 32-bit word == 0.
// ---------------------------------------------------------------------------
__device__ __forceinline__ long long edge_at(const void* edges, int is64, long long i) {
    if (is64) return ((const long long*)edges)[i];
    return (long long)((const int*)edges)[i];
}

__global__ void k_detect_dtype(const void* edges, int* flag) {
    if (threadIdx.x == 0 && blockIdx.x == 0) {
        const int* w = (const int*)edges;
        int is64 = 1;
        for (int i = 0; i < 16; ++i) {
            if (w[2 * i + 1] != 0) { is64 = 0; break; }
        }
        *flag = is64;
    }
}

// deg[dst[e]]++ for each real edge (deg zeroed via hipMemsetAsync)
__global__ void k_count(const void* edges, const int* flag, int* deg, long long E) {
    long long e = blockIdx.x * 256LL + threadIdx.x;
    if (e >= E) return;
    long long d = edge_at(edges, *flag, E + e);
    atomicAdd(&deg[d], 1);
}

// ---------------------------------------------------------------------------
// 3-phase multi-block exclusive scan of deg[N] (in degoffs, in place).
// Phase A also computes dinv = rsqrt(deg+1)  (self-loop folded into degree).
// ---------------------------------------------------------------------------
__global__ __launch_bounds__(256) void k_scan_partial(const int* __restrict__ deg,
                                                      float* __restrict__ dinv,
                                                      int* __restrict__ partials, int N) {
    int i = blockIdx.x * 256 + threadIdx.x;
    int t = threadIdx.x;
    int v = (i < N) ? deg[i] : 0;
    if (i < N) dinv[i] = rsqrtf((float)v + 1.0f);
    __shared__ int s[256];
    s[t] = v;
    __syncthreads();
    for (int d = 128; d > 0; d >>= 1) {
        if (t < d) s[t] += s[t + d];
        __syncthreads();
    }
    if (t == 0) partials[blockIdx.x] = s[0];
}

// single block: exclusive scan of nb (<=256) partials in place
__global__ __launch_bounds__(256) void k_scan_partials(int* partials, int nb) {
    __shared__ int s[256];
    int t = threadIdx.x;
    int v = (t < nb) ? partials[t] : 0;
    s[t] = v;
    __syncthreads();
    for (int d = 1; d < 256; d <<= 1) {
        int u = (t >= d) ? s[t - d] : 0;
        __syncthreads();
        s[t] += u;
        __syncthreads();
    }
    if (t < nb) partials[t] = s[t] - v;   // exclusive
}

// per-block local scan + base offset; writes offsets (in place) + cursor copy
__global__ __launch_bounds__(256) void k_scan_apply(int* degoffs, int* cursor,
                                                    const int* __restrict__ partials, int N) {
    int i = blockIdx.x * 256 + threadIdx.x;
    int t = threadIdx.x;
    int v = (i < N) ? degoffs[i] : 0;
    __shared__ int s[256];
    s[t] = v;
    __syncthreads();
    for (int d = 1; d < 256; d <<= 1) {
        int u = (t >= d) ? s[t - d] : 0;
        __syncthreads();
        s[t] += u;
        __syncthreads();
    }
    int off = partials[blockIdx.x] + s[t] - v;   // exclusive offset
    if (i < N) { degoffs[i] = off; cursor[i] = off; }
    if (i == N - 1) degoffs[N] = off + v;
}

// CSR build with fused weight: csr[pos] = {src, bits(dinv[src])}
__global__ void k_place(const void* edges, const int* flag, const float* __restrict__ dinv,
                        int* cursor, int2* csr, long long E) {
    long long e = blockIdx.x * 256LL + threadIdx.x;
    if (e >= E) return;
    int is64 = *flag;
    int s = (int)edge_at(edges, is64, e);
    int d = (int)edge_at(edges, is64, E + e);
    int pos = atomicAdd(&cursor[d], 1);
    csr[pos] = make_int2(s, __float_as_int(dinv[s]));
}

// ---------------------------------------------------------------------------
// Fused layer 1: gather-aggregate x + GEMM1(+b1,ReLU) + GEMM2, one wave/node.
// h2[i][:] = relu( dinv_i*(dinv_i*x_i + sum_s dinv_s*x_s) @ W1 + b1 ) @ W2
// ---------------------------------------------------------------------------
__global__ __launch_bounds__(256) void k_l1_fused(
    const float* __restrict__ x, const float* __restrict__ dinv,
    const int* __restrict__ offs, const int2* __restrict__ csr,
    const float* __restrict__ W1, const float* __restrict__ b1,
    const float* __restrict__ W2, float* __restrict__ h2, int N)
{
    __shared__ float W1s[IN_DIM * HID_DIM];   // 4 KB
    __shared__ float W2s[HID_DIM * OUT_DIM];  // 8 KB
    int tid = threadIdx.x;
    for (int i = tid; i < IN_DIM * HID_DIM; i += 256) W1s[i] = W1[i];
    for (int i = tid; i < HID_DIM * OUT_DIM; i += 256) W2s[i] = W2[i];
    __syncthreads();

    int node = (blockIdx.x * 256 + tid) >> 6;
    if (node >= N) return;
    int lane = tid & 63;
    int c = lane & 15, j0 = lane >> 4;        // 16 channels x 4 edge-ways
    float di = dinv[node];
    int start = offs[node], end = offs[node + 1];
    float acc = (j0 == 0) ? di * x[node * IN_DIM + c] : 0.f;
    for (int j = start + j0; j < end; j += 4) {
        int2 p = csr[j];
        acc += __int_as_float(p.y) * x[p.x * IN_DIM + c];
    }
    acc += __shfl_xor(acc, 16, 64);
    acc += __shfl_xor(acc, 32, 64);           // all lanes: agg[lane&15]
    acc *= di;

    // h1[col], col = lane in [0,64): broadcast agg[k] via shfl
    float h1v = b1[lane];
    #pragma unroll
    for (int k = 0; k < IN_DIM; ++k)
        h1v += __shfl(acc, k, 64) * W1s[k * HID_DIM + lane];
    h1v = fmaxf(h1v, 0.f);

    // h2[col2], col2 = lane&31; each half sums 32 of the 64 k-terms
    int col2 = lane & 31, half = lane >> 5;
    float h2v = 0.f;
    #pragma unroll
    for (int k = 0; k < 32; ++k) {
        int kk = half * 32 + k;
        h2v += __shfl(h1v, kk, 64) * W2s[kk * OUT_DIM + col2];
    }
    h2v += __shfl_xor(h2v, 32, 64);
    if (lane < 32) h2[node * OUT_DIM + col2] = h2v;
}

// Layer-2 gather-aggregate: one wave per node, lanes = 32 ch x 2 edge-ways.
// out[i][c] = b2[c] + dinv_i*(dinv_i*h2[i][c] + sum_s dinv_s*h2[s][c])
__global__ __launch_bounds__(256) void k_agg2(
    const float* __restrict__ h2, const float* __restrict__ dinv,
    const int* __restrict__ offs, const int2* __restrict__ csr,
    const float* __restrict__ b2, float* __restrict__ out, int N)
{
    int node = (blockIdx.x * 256 + threadIdx.x) >> 6;
    if (node >= N) return;
    int lane = threadIdx.x & 63;
    int c = lane & 31, j0 = lane >> 5;
    float di = dinv[node];
    int start = offs[node], end = offs[node + 1];
    float acc = (j0 == 0) ? di * h2[node * OUT_DIM + c] : 0.f;
    for (int j = start + j0; j < end; j += 2) {
        int2 p = csr[j];
        acc += __int_as_float(p.y) * h2[p.x * OUT_DIM + c];
    }
    acc += __shfl_xor(acc, 32, 64);
    if (lane < 32) out[node * OUT_DIM + c] = di * acc + b2[c];
}

extern "C" void kernel_launch(void* const* d_in, const int* in_sizes, int n_in,
                              void* d_out, int out_size, void* d_ws, size_t ws_size,
                              hipStream_t stream) {
    const float* x     = (const float*)d_in[0];
    const void*  edges = d_in[1];
    const float* W1    = (const float*)d_in[2];
    const float* b1    = (const float*)d_in[3];
    const float* W2    = (const float*)d_in[4];
    const float* b2    = (const float*)d_in[5];
    float* out = (float*)d_out;

    const int       N = in_sizes[0] / IN_DIM;   // 50000
    const long long E = in_sizes[1] / 2;        // 800000
    const int      NB = (N + 255) / 256;        // 196 scan blocks (<=256 required)

    // workspace layout (8B-aligned first): csr [E int2] | h2 [32N f] | dinv [N f]
    //   | degoffs [N+1] | cursor [N] | partials [256] | flag [1]
    int2*  csr     = (int2*)d_ws;
    float* h2      = (float*)(csr + E);
    float* dinv    = h2 + (size_t)OUT_DIM * N;
    int*   degoffs = (int*)(dinv + N);
    int*   cursor  = degoffs + N + 1;
    int*   partials = cursor + N;
    int*   flag     = partials + 256;

    const int B = 256;
    k_detect_dtype<<<1, 1, 0, stream>>>(edges, flag);
    hipMemsetAsync(degoffs, 0, (size_t)(N + 1) * sizeof(int), stream);
    k_count<<<(int)((E + B - 1) / B), B, 0, stream>>>(edges, flag, degoffs, E);
    k_scan_partial<<<NB, B, 0, stream>>>(degoffs, dinv, partials, N);
    k_scan_partials<<<1, B, 0, stream>>>(partials, NB);
    k_scan_apply<<<NB, B, 0, stream>>>(degoffs, cursor, partials, N);
    k_place<<<(int)((E + B - 1) / B), B, 0, stream>>>(edges, flag, dinv, cursor, csr, E);

    // one wave per node -> 4 nodes per 256-thread block
    k_l1_fused<<<(N + 3) / 4, B, 0, stream>>>(x, dinv, degoffs, csr, W1, b1, W2, h2, N);
    k_agg2<<<(N + 3) / 4, B, 0, stream>>>(h2, dinv, degoffs, csr, b2, out, N);
}

// Round 4
// 235.303 us; speedup vs baseline: 1.6551x; 1.1131x over previous
//
#include <hip/hip_runtime.h>

#define IN_DIM  16
#define HID_DIM 64
#define OUT_DIM 32

// ---------------------------------------------------------------------------
// Edge dtype: reference says int64, harness doc says int32. Detect inline:
// nonneg int64 < 2^31 has every odd 32-bit word == 0.
// ---------------------------------------------------------------------------
__device__ __forceinline__ int detect_is64(const void* edges) {
    const int* w = (const int*)edges;
    int is64 = 1;
    #pragma unroll
    for (int i = 0; i < 16; ++i) is64 &= (w[2 * i + 1] == 0);
    return is64;
}

__device__ __forceinline__ long long edge_at(const void* edges, int is64, long long i) {
    if (is64) return ((const long long*)edges)[i];
    return (long long)((const int*)edges)[i];
}

// deg[dst[e]]++ for each real edge (deg zeroed via hipMemsetAsync)
__global__ void k_count(const void* edges, int* deg, long long E) {
    __shared__ int s64;
    if (threadIdx.x == 0) s64 = detect_is64(edges);
    __syncthreads();
    long long e = blockIdx.x * 256LL + threadIdx.x;
    if (e >= E) return;
    long long d = edge_at(edges, s64, E + e);
    atomicAdd(&deg[d], 1);
}

// ---------------------------------------------------------------------------
// 3-phase multi-block exclusive scan of deg[N]. Phase A also computes
// dinv = rsqrt(deg+1) (self-loop folded into degree).
// ---------------------------------------------------------------------------
__global__ __launch_bounds__(256) void k_scan_partial(const int* __restrict__ deg,
                                                      float* __restrict__ dinv,
                                                      int* __restrict__ partials, int N) {
    int i = blockIdx.x * 256 + threadIdx.x;
    int t = threadIdx.x;
    int v = (i < N) ? deg[i] : 0;
    if (i < N) dinv[i] = rsqrtf((float)v + 1.0f);
    __shared__ int s[256];
    s[t] = v;
    __syncthreads();
    for (int d = 128; d > 0; d >>= 1) {
        if (t < d) s[t] += s[t + d];
        __syncthreads();
    }
    if (t == 0) partials[blockIdx.x] = s[0];
}

__global__ __launch_bounds__(256) void k_scan_partials(int* partials, int nb) {
    __shared__ int s[256];
    int t = threadIdx.x;
    int v = (t < nb) ? partials[t] : 0;
    s[t] = v;
    __syncthreads();
    for (int d = 1; d < 256; d <<= 1) {
        int u = (t >= d) ? s[t - d] : 0;
        __syncthreads();
        s[t] += u;
        __syncthreads();
    }
    if (t < nb) partials[t] = s[t] - v;   // exclusive
}

__global__ __launch_bounds__(256) void k_scan_apply(int* degoffs, int* cursor,
                                                    const int* __restrict__ partials, int N) {
    int i = blockIdx.x * 256 + threadIdx.x;
    int t = threadIdx.x;
    int v = (i < N) ? degoffs[i] : 0;
    __shared__ int s[256];
    s[t] = v;
    __syncthreads();
    for (int d = 1; d < 256; d <<= 1) {
        int u = (t >= d) ? s[t - d] : 0;
        __syncthreads();
        s[t] += u;
        __syncthreads();
    }
    int off = partials[blockIdx.x] + s[t] - v;   // exclusive offset
    if (i < N) { degoffs[i] = off; cursor[i] = off; }
    if (i == N - 1) degoffs[N] = off + v;
}

// CSR build with fused weight: csr[pos] = {src, bits(dinv[src])}
__global__ void k_place(const void* edges, const float* __restrict__ dinv,
                        int* cursor, int2* csr, long long E) {
    __shared__ int s64;
    if (threadIdx.x == 0) s64 = detect_is64(edges);
    __syncthreads();
    long long e = blockIdx.x * 256LL + threadIdx.x;
    if (e >= E) return;
    int s = (int)edge_at(edges, s64, e);
    int d = (int)edge_at(edges, s64, E + e);
    int pos = atomicAdd(&cursor[d], 1);
    csr[pos] = make_int2(s, __float_as_int(dinv[s]));
}

// ---------------------------------------------------------------------------
// Fused layer 1: gather-aggregate x + GEMM1(+b1,ReLU) + GEMM2, one wave/node,
// 4 lanes per edge (float4), 16 edge-ways -> avg-deg-16 node = 1 iteration.
// Each block handles 16 nodes (4 per wave) to amortize 12 KB weight staging.
// ---------------------------------------------------------------------------
__global__ __launch_bounds__(256) void k_l1_fused(
    const float* __restrict__ x, const float* __restrict__ dinv,
    const int* __restrict__ offs, const int2* __restrict__ csr,
    const float* __restrict__ W1, const float* __restrict__ b1,
    const float* __restrict__ W2, float* __restrict__ h2, int N)
{
    __shared__ float W1s[IN_DIM * HID_DIM];   // 4 KB
    __shared__ float W2s[HID_DIM * OUT_DIM];  // 8 KB
    int tid = threadIdx.x;
    for (int i = tid; i < IN_DIM * HID_DIM; i += 256) W1s[i] = W1[i];
    for (int i = tid; i < HID_DIM * OUT_DIM; i += 256) W2s[i] = W2[i];
    __syncthreads();

    int lane = tid & 63, wid = tid >> 6;
    int comp = lane & 3;      // which float4 quad of the 16-ch row
    int g    = lane >> 2;     // edge way, 0..15
    const float4* x4 = (const float4*)x;

    for (int it = 0; it < 4; ++it) {
        int node = blockIdx.x * 16 + wid * 4 + it;
        if (node >= N) continue;
        float di = dinv[node];
        int start = offs[node], end = offs[node + 1];
        float4 acc = make_float4(0.f, 0.f, 0.f, 0.f);
        if (g == 0) {
            float4 xs = x4[node * 4 + comp];
            acc = make_float4(di * xs.x, di * xs.y, di * xs.z, di * xs.w);
        }
        for (int j = start + g; j < end; j += 16) {
            int2 p = csr[j];
            float w = __int_as_float(p.y);
            float4 xv = x4[p.x * 4 + comp];
            acc.x += w * xv.x; acc.y += w * xv.y;
            acc.z += w * xv.z; acc.w += w * xv.w;
        }
        #pragma unroll
        for (int m = 4; m < 64; m <<= 1) {
            acc.x += __shfl_xor(acc.x, m, 64);
            acc.y += __shfl_xor(acc.y, m, 64);
            acc.z += __shfl_xor(acc.z, m, 64);
            acc.w += __shfl_xor(acc.w, m, 64);
        }
        float vals[4] = {di * acc.x, di * acc.y, di * acc.z, di * acc.w};

        // h1[col], col = lane: channel k lives in lane (k>>2), component (k&3)
        float h1v = b1[lane];
        #pragma unroll
        for (int k = 0; k < IN_DIM; ++k)
            h1v += __shfl(vals[k & 3], k >> 2, 64) * W1s[k * HID_DIM + lane];
        h1v = fmaxf(h1v, 0.f);

        // h2[col2], col2 = lane&31; each half sums 32 of the 64 k-terms
        int col2 = lane & 31, half = lane >> 5;
        float h2v = 0.f;
        #pragma unroll
        for (int k = 0; k < 32; ++k) {
            int kk = half * 32 + k;
            h2v += __shfl(h1v, kk, 64) * W2s[kk * OUT_DIM + col2];
        }
        h2v += __shfl_xor(h2v, 32, 64);
        if (lane < 32) h2[node * OUT_DIM + col2] = h2v;
    }
}

// ---------------------------------------------------------------------------
// Layer-2 gather: one wave/node, 8 lanes per edge (float4), 8 edge-ways.
// out[i][c] = b2[c] + dinv_i*(dinv_i*h2[i][c] + sum_s dinv_s*h2[s][c])
// ---------------------------------------------------------------------------
__global__ __launch_bounds__(256) void k_agg2(
    const float* __restrict__ h2, const float* __restrict__ dinv,
    const int* __restrict__ offs, const int2* __restrict__ csr,
    const float* __restrict__ b2, float* __restrict__ out, int N)
{
    int node = (blockIdx.x * 256 + threadIdx.x) >> 6;
    if (node >= N) return;
    int lane = threadIdx.x & 63;
    int comp = lane & 7;      // which float4 quad of the 32-ch row
    int g    = lane >> 3;     // edge way, 0..7
    const float4* h24 = (const float4*)h2;
    float di = dinv[node];
    int start = offs[node], end = offs[node + 1];
    float4 acc = make_float4(0.f, 0.f, 0.f, 0.f);
    if (g == 0) {
        float4 v = h24[node * 8 + comp];
        acc = make_float4(di * v.x, di * v.y, di * v.z, di * v.w);
    }
    for (int j = start + g; j < end; j += 8) {
        int2 p = csr[j];
        float w = __int_as_float(p.y);
        float4 v = h24[p.x * 8 + comp];
        acc.x += w * v.x; acc.y += w * v.y;
        acc.z += w * v.z; acc.w += w * v.w;
    }
    #pragma unroll
    for (int m = 8; m < 64; m <<= 1) {
        acc.x += __shfl_xor(acc.x, m, 64);
        acc.y += __shfl_xor(acc.y, m, 64);
        acc.z += __shfl_xor(acc.z, m, 64);
        acc.w += __shfl_xor(acc.w, m, 64);
    }
    if (g == 0) {
        float4 bb = ((const float4*)b2)[comp];
        float4 o = make_float4(di * acc.x + bb.x, di * acc.y + bb.y,
                               di * acc.z + bb.z, di * acc.w + bb.w);
        ((float4*)out)[node * 8 + comp] = o;
    }
}

extern "C" void kernel_launch(void* const* d_in, const int* in_sizes, int n_in,
                              void* d_out, int out_size, void* d_ws, size_t ws_size,
                              hipStream_t stream) {
    const float* x     = (const float*)d_in[0];
    const void*  edges = d_in[1];
    const float* W1    = (const float*)d_in[2];
    const float* b1    = (const float*)d_in[3];
    const float* W2    = (const float*)d_in[4];
    const float* b2    = (const float*)d_in[5];
    float* out = (float*)d_out;

    const int       N = in_sizes[0] / IN_DIM;   // 50000
    const long long E = in_sizes[1] / 2;        // 800000
    const int      NB = (N + 255) / 256;        // scan blocks (<=256 required)

    // workspace layout (16B-aligned first): csr [E int2] | h2 [32N f] | dinv [N f]
    //   | degoffs [N+1] | cursor [N] | partials [256]
    int2*  csr      = (int2*)d_ws;
    float* h2       = (float*)(csr + E);
    float* dinv     = h2 + (size_t)OUT_DIM * N;
    int*   degoffs  = (int*)(dinv + N);
    int*   cursor   = degoffs + N + 1;
    int*   partials = cursor + N;

    const int B = 256;
    hipMemsetAsync(degoffs, 0, (size_t)(N + 1) * sizeof(int), stream);
    k_count<<<(int)((E + B - 1) / B), B, 0, stream>>>(edges, degoffs, E);
    k_scan_partial<<<NB, B, 0, stream>>>(degoffs, dinv, partials, N);
    k_scan_partials<<<1, B, 0, stream>>>(partials, NB);
    k_scan_apply<<<NB, B, 0, stream>>>(degoffs, cursor, partials, N);
    k_place<<<(int)((E + B - 1) / B), B, 0, stream>>>(edges, dinv, cursor, csr, E);

    k_l1_fused<<<(N + 15) / 16, B, 0, stream>>>(x, dinv, degoffs, csr, W1, b1, W2, h2, N);
    k_agg2<<<(N + 3) / 4, B, 0, stream>>>(h2, dinv, degoffs, csr, b2, out, N);
}